// Round 16
// baseline (144.574 us; speedup 1.0000x reference)
//
#include <hip/hip_runtime.h>

// SSIM loss, fused. Input: enhanced, target fp32 [16,3,512,512]. Output: scalar fp32.
// V18 = V17 (barrier-free wave-independent, interleaved float4 LDS, pk_fma,
// rcp-NR) + VERTICAL WAVE-CHAINING: one wave = 16 cols x 64 rows (4 chunks of
// 16), 32-row LDS ring (&31 exact: chain base = 64*cy == 0 mod 32). The 6-row
// h-filtered halo is REUSED across chunks: h-items 176 -> 140 per 16x64 (-20%),
// loads likewise. Zero barriers: same-wave DS ops are hardware-in-order, so
// ring write->read->overwrite is safe by program order (22-row live window
// <= 32-row ring: no mod-32 aliasing). With no barriers and no forced
// cross-phase state, the compiler may hoist next-chunk global loads above the
// current v-pass electively (no spill risk: hoisting is optional).

#define HALO 3
#define SLOTS 17                     // float4 slots/row (16 + 1 pad)
#define RING 32                      // ring rows (power of 2)
#define IMG_H 512
#define IMG_W 512
#define NPLANES 48                   // 16 * 3
#define SSIM_C1 1.0e-4f
#define SSIM_C2 9.0e-4f

static __device__ constexpr float G[7] = {
    0.03663284536f, 0.11128076166f, 0.21674531251f, 0.27068216094f,
    0.21674531251f, 0.11128076166f, 0.03663284536f};

// Packed fp32 FMA: d.lo = fma(a.lo,b.lo,c.lo), d.hi = fma(a.hi,b.hi,c.hi).
__device__ __forceinline__ float2 pk_fma(const float2 a, const float2 b,
                                         const float2 c) {
  float2 d;
  asm("v_pk_fma_f32 %0, %1, %2, %3" : "=v"(d) : "v"(a), "v"(b), "v"(c));
  return d;
}

// Aligned float4 load with zero fill outside [0, IMG_W). col is a multiple of 4.
__device__ __forceinline__ float4 ld4z(const float* __restrict__ row, int col) {
  if (col >= 0 && col + 3 < IMG_W) {
    return *reinterpret_cast<const float4*>(row + col);
  }
  float4 v;
  v.x = ((unsigned)(col + 0) < IMG_W) ? row[col + 0] : 0.f;
  v.y = ((unsigned)(col + 1) < IMG_W) ? row[col + 1] : 0.f;
  v.z = ((unsigned)(col + 2) < IMG_W) ? row[col + 2] : 0.f;
  v.w = ((unsigned)(col + 3) < IMG_W) ? row[col + 3] : 0.f;
  return v;
}

__global__ __launch_bounds__(256, 4) void ssim_chain_kernel(
    const float* __restrict__ x, const float* __restrict__ y,
    float* __restrict__ partial) {
  // Per-wave ring: one float4 = (mu1, mu2, S, XY) per (ring row, col).
  __shared__ __align__(16) float4 ring[4][RING][SLOTS];  // 34,816 B -> 4 blk/CU
  __shared__ float wsum[4];

  const int tid = threadIdx.x;
  const int wid = tid >> 6;
  const int lane = tid & 63;
  const int tx = blockIdx.x * 4 + wid;   // [0,32): 16-col strips
  const int cy = blockIdx.y;             // [0,8): 64-row chains
  const int plane = blockIdx.z;
  const float* __restrict__ xp = x + (size_t)plane * (IMG_H * IMG_W);
  const float* __restrict__ yp = y + (size_t)plane * (IMG_H * IMG_W);
  const int x0 = tx * 16;
  const int yb = cy * 64;                // == 0 mod 32 -> ring idx = rel & 31
  const bool edge_x = (tx == 0) | (tx == 31);
  float4(*rb)[SLOTS] = ring[wid];

  // ---- Horizontal 7-tap for a batch of rows [gr0, gr0+nrows).
  // Lane = (row lane>>1, col-group lane&1); 16-float window [x0+8cg-4 .. +11];
  // output j (0..7) uses window indices j+1..j+7. Writes ring[gy&31][8cg+j].
  auto h_rows = [&](int gr0, int nrows, bool edgey) {
    if (lane < 2 * nrows) {
      const int gy = gr0 + (lane >> 1);
      const int cg = lane & 1;
      const int bcol = x0 + 8 * cg - 4;
      const bool edge = edge_x | edgey;
      float4 xv0, xv1, xv2, xv3, yv0, yv1, yv2, yv3;
      if (!edge) {
        const float* xr = xp + (size_t)gy * IMG_W + bcol;
        const float* yr = yp + (size_t)gy * IMG_W + bcol;
        xv0 = *reinterpret_cast<const float4*>(xr);
        xv1 = *reinterpret_cast<const float4*>(xr + 4);
        xv2 = *reinterpret_cast<const float4*>(xr + 8);
        xv3 = *reinterpret_cast<const float4*>(xr + 12);
        yv0 = *reinterpret_cast<const float4*>(yr);
        yv1 = *reinterpret_cast<const float4*>(yr + 4);
        yv2 = *reinterpret_cast<const float4*>(yr + 8);
        yv3 = *reinterpret_cast<const float4*>(yr + 12);
      } else if ((unsigned)gy < IMG_H) {
        const float* xr = xp + (size_t)gy * IMG_W;
        const float* yr = yp + (size_t)gy * IMG_W;
        xv0 = ld4z(xr, bcol);
        xv1 = ld4z(xr, bcol + 4);
        xv2 = ld4z(xr, bcol + 8);
        xv3 = ld4z(xr, bcol + 12);
        yv0 = ld4z(yr, bcol);
        yv1 = ld4z(yr, bcol + 4);
        yv2 = ld4z(yr, bcol + 8);
        yv3 = ld4z(yr, bcol + 12);
      } else {
        const float4 z = make_float4(0.f, 0.f, 0.f, 0.f);
        xv0 = xv1 = xv2 = xv3 = z;
        yv0 = yv1 = yv2 = yv3 = z;
      }
      const float wx[16] = {xv0.x, xv0.y, xv0.z, xv0.w, xv1.x, xv1.y, xv1.z,
                            xv1.w, xv2.x, xv2.y, xv2.z, xv2.w, xv3.x, xv3.y,
                            xv3.z, xv3.w};
      const float wy[16] = {yv0.x, yv0.y, yv0.z, yv0.w, yv1.x, yv1.y, yv1.z,
                            yv1.w, yv2.x, yv2.y, yv2.z, yv2.w, yv3.x, yv3.y,
                            yv3.z, yv3.w};
      float2 A[8], B[8];
#pragma unroll
      for (int j = 0; j < 8; ++j) {
        A[j] = make_float2(0.f, 0.f);
        B[j] = make_float2(0.f, 0.f);
      }
#pragma unroll
      for (int wi = 1; wi < 15; ++wi) {
        const float xv = wx[wi];
        const float yv = wy[wi];
        const float2 xyp = make_float2(xv, yv);
        const float2 spp = make_float2(fmaf(xv, xv, yv * yv), xv * yv);
#pragma unroll
        for (int j = 0; j < 8; ++j) {
          const int k = wi - 1 - j;  // tap index for output col j
          if (k >= 0 && k < 7) {
            const float2 gk2 = make_float2(G[k], G[k]);
            A[j] = pk_fma(gk2, xyp, A[j]);
            B[j] = pk_fma(gk2, spp, B[j]);
          }
        }
      }
      const int rr = gy & (RING - 1);
#pragma unroll
      for (int j = 0; j < 8; ++j) {
        rb[rr][8 * cg + j] = make_float4(A[j].x, A[j].y, B[j].x, B[j].y);
      }
    }
  };

  // ---- Vertical 7-tap + SSIM map for chunk i (output rows yb+16i .. +15).
  // Lane = (col c = lane&15, 4-row group rg = lane>>4).
  const int c = lane & 15;
  const int rg = lane >> 4;
  auto v_chunk = [&](int i) -> float {
    float2 M[4], S4[4];
#pragma unroll
    for (int t = 0; t < 4; ++t) {
      M[t] = make_float2(0.f, 0.f);
      S4[t] = make_float2(0.f, 0.f);
    }
#pragma unroll
    for (int j = 0; j < 10; ++j) {  // input rel rows 16i+4rg-3+j
      const float4 v = rb[(16 * i + 4 * rg - 3 + j) & (RING - 1)][c];
      const float2 mv = make_float2(v.x, v.y);
      const float2 sv = make_float2(v.z, v.w);
#pragma unroll
      for (int t = 0; t < 4; ++t) {
        const int k = j - t;  // tap index for output row 16i+4rg+t
        if (k >= 0 && k < 7) {
          const float2 gk2 = make_float2(G[k], G[k]);
          M[t] = pk_fma(gk2, mv, M[t]);
          S4[t] = pk_fma(gk2, sv, S4[t]);
        }
      }
    }
    float a = 0.f;
#pragma unroll
    for (int t = 0; t < 4; ++t) {
      const float mu1 = M[t].x, mu2 = M[t].y;
      const float mu12 = mu1 * mu2;
      const float msq = fmaf(mu1, mu1, mu2 * mu2);  // mu1^2 + mu2^2
      const float sig12 = S4[t].y - mu12;
      const float sigsum = S4[t].x - msq;           // sigma1 + sigma2
      const float num = fmaf(2.f, mu12, SSIM_C1) * fmaf(2.f, sig12, SSIM_C2);
      const float den = (msq + SSIM_C1) * (sigsum + SSIM_C2);
      float r = __builtin_amdgcn_rcpf(den);  // den > 0 always
      r = r * fmaf(-den, r, 2.f);            // 1 Newton step, ~1 ulp
      a = fmaf(num, r, a);
    }
    return a;
  };

  // ---- Chain: prologue fills 22 h-rows; each later chunk adds 16 (halo
  // reuse). No barriers anywhere: same-wave DS ops are in-order, and the
  // 22-row live window fits the 32-row ring without mod-32 aliasing.
  float acc = 0.f;
  h_rows(yb - 3, 22, cy == 0);           // rel rows -3..18
  acc += v_chunk(0);
  h_rows(yb + 19, 16, false);            // rel 19..34
  acc += v_chunk(1);
  h_rows(yb + 35, 16, false);            // rel 35..50
  acc += v_chunk(2);
  h_rows(yb + 51, 16, cy == 7);          // rel 51..66 (bottom clamp via ld4z)
  acc += v_chunk(3);

  // Wave reduce, then one block combine (the only __syncthreads, at the end).
#pragma unroll
  for (int off = 32; off > 0; off >>= 1) acc += __shfl_down(acc, off, 64);
  if (lane == 0) wsum[wid] = acc;
  __syncthreads();
  if (tid == 0) {
    partial[((size_t)plane * 8 + blockIdx.y) * 8 + blockIdx.x] =
        wsum[0] + wsum[1] + wsum[2] + wsum[3];
  }
}

__global__ __launch_bounds__(1024) void ssim_reduce_kernel(
    const float* __restrict__ partial, int n, float* __restrict__ out) {
  float acc = 0.f;
  const int nv = n >> 2;  // n = 3072 -> 768 float4
  const float4* __restrict__ p4 = reinterpret_cast<const float4*>(partial);
  for (int i = threadIdx.x; i < nv; i += 1024) {
    const float4 v = p4[i];
    acc += (v.x + v.y) + (v.z + v.w);
  }
#pragma unroll
  for (int off = 32; off > 0; off >>= 1) acc += __shfl_down(acc, off, 64);
  __shared__ float wsum[16];
  if ((threadIdx.x & 63) == 0) wsum[threadIdx.x >> 6] = acc;
  __syncthreads();
  if (threadIdx.x == 0) {
    float s = 0.f;
#pragma unroll
    for (int w = 0; w < 16; ++w) s += wsum[w];
    out[0] = 1.f - s * (1.f / (float)(NPLANES * IMG_H * IMG_W));
  }
}

extern "C" void kernel_launch(void* const* d_in, const int* in_sizes, int n_in,
                              void* d_out, int out_size, void* d_ws, size_t ws_size,
                              hipStream_t stream) {
  const float* enhanced = (const float*)d_in[0];
  const float* target = (const float*)d_in[1];
  float* out = (float*)d_out;
  float* partial = (float*)d_ws;

  dim3 grid(8, 8, NPLANES);  // 8 x 8 x 48 = 3072 blocks (4 wave-chains each)
  dim3 block(256, 1, 1);
  ssim_chain_kernel<<<grid, block, 0, stream>>>(enhanced, target, partial);

  const int nblocks = 8 * 8 * NPLANES;  // 3072
  ssim_reduce_kernel<<<1, 1024, 0, stream>>>(partial, nblocks, out);
}